// Round 1
// baseline (321.241 us; speedup 1.0000x reference)
//
#include <hip/hip_runtime.h>
#include <hip/hip_bf16.h>

#define BB 4
#define CC 128
#define NN 4096
#define HH 4
#define HD 32
#define NTOK (BB*NN)

typedef float f32x4 __attribute__((ext_vector_type(4)));
typedef short bf16x8 __attribute__((ext_vector_type(8)));
typedef unsigned short u16;
typedef unsigned int u32;

__device__ __forceinline__ u16 f2bf(float f) {
    union { float f; u32 u; } v; v.f = f;
    u32 r = v.u + 0x7FFF + ((v.u >> 16) & 1);
    return (u16)(r >> 16);
}

// ---------------- Kernel 1: transposes (x -> t_bf token-major, W -> Wt) ----------------
__global__ __launch_bounds__(256) void prep_kernel(const float* __restrict__ x,
                                                   const float* __restrict__ W,
                                                   u16* __restrict__ t_bf,
                                                   u16* __restrict__ Wt_bf) {
    __shared__ u16 tile[64][65];
    int blk = blockIdx.x;
    const float* src; u16* dst; int src_cols, dst_cols, r0, c0;
    if (blk < 512) {
        int b  = blk >> 7;
        int rem = blk & 127;
        int ct = rem >> 6;      // c-tile (rows of x): 0..1
        int nt = rem & 63;      // n-tile (cols of x): 0..63
        src = x + b * CC * NN;  src_cols = NN; r0 = ct * 64; c0 = nt * 64;
        dst = t_bf + b * NN * CC; dst_cols = CC;
    } else {
        int rem = blk - 512;    // 0..11
        int kt = rem / 6, nt = rem % 6;
        src = W; src_cols = 3 * CC; r0 = kt * 64; c0 = nt * 64;
        dst = Wt_bf; dst_cols = CC;
    }
    int t = threadIdx.x;
#pragma unroll
    for (int p = 0; p < 16; ++p) {
        int rl = p * 4 + (t >> 6);
        int cl = t & 63;
        tile[rl][cl] = f2bf(src[(r0 + rl) * src_cols + c0 + cl]);
    }
    __syncthreads();
#pragma unroll
    for (int p = 0; p < 16; ++p) {
        int cl = p * 4 + (t >> 6);
        int rl = t & 63;
        dst[(c0 + cl) * dst_cols + r0 + rl] = tile[rl][cl];
    }
}

// ---------------- Kernel 2: QKV GEMM (M=16384, N=384, K=128) ----------------
__global__ __launch_bounds__(256, 2) void qkv_gemm(const u16* __restrict__ t_bf,
                                                   const u16* __restrict__ Wt_bf,
                                                   const float* __restrict__ bias,
                                                   u16* __restrict__ Qb,
                                                   u16* __restrict__ Kb,
                                                   u16* __restrict__ Vb) {
    __shared__ u16 Al[128 * 128];
    __shared__ u16 Bl[128 * 128];
    int mt = blockIdx.x;   // 0..127
    int nt = blockIdx.y;   // 0..2 -> Q/K/V
    int t = threadIdx.x;

    {   // stage A and B, XOR-swizzled 16B chunks (chunk ^= row&7)
        const uint4* srcA = (const uint4*)(t_bf + mt * 128 * 128);
        const uint4* srcB = (const uint4*)(Wt_bf + nt * 128 * 128);
#pragma unroll
        for (int p = 0; p < 8; ++p) {
            int cid = p * 256 + t;
            int row = cid >> 4, c16 = cid & 15;
            int sw = (c16 ^ (row & 7)) * 8;
            *(uint4*)(Al + row * 128 + sw) = srcA[cid];
            *(uint4*)(Bl + row * 128 + sw) = srcB[cid];
        }
    }
    __syncthreads();

    int w = t >> 6, l = t & 63;
    int wq = (w >> 1) * 64, wn = (w & 1) * 64;
    int lr = l & 15, lg = l >> 4;

    f32x4 acc[4][4];
#pragma unroll
    for (int mi = 0; mi < 4; ++mi)
#pragma unroll
        for (int ni = 0; ni < 4; ++ni)
            acc[mi][ni] = f32x4{0.f, 0.f, 0.f, 0.f};

#pragma unroll
    for (int kk = 0; kk < 4; ++kk) {
        bf16x8 a[4], bb[4];
        int c = kk * 4 + lg;   // 16B chunk index along k
#pragma unroll
        for (int mi = 0; mi < 4; ++mi) {
            int R = wq + mi * 16 + lr;
            a[mi] = *(const bf16x8*)(Al + R * 128 + ((c ^ (R & 7)) * 8));
        }
#pragma unroll
        for (int ni = 0; ni < 4; ++ni) {
            int R = wn + ni * 16 + lr;
            bb[ni] = *(const bf16x8*)(Bl + R * 128 + ((c ^ (R & 7)) * 8));
        }
#pragma unroll
        for (int mi = 0; mi < 4; ++mi)
#pragma unroll
            for (int ni = 0; ni < 4; ++ni)
                acc[mi][ni] = __builtin_amdgcn_mfma_f32_16x16x32_bf16(a[mi], bb[ni], acc[mi][ni], 0, 0, 0);
    }

    // epilogue: +bias, scale Q by 1/sqrt(32), store token-major [b][h][i][d]
    int b = mt >> 5;
    int tok0 = (mt & 31) * 128 + wq;
    u16* outbuf = (nt == 0) ? Qb : (nt == 1 ? Kb : Vb);
    float qscale = (nt == 0) ? 0.17677669529663687f : 1.0f;
#pragma unroll
    for (int mi = 0; mi < 4; ++mi)
#pragma unroll
        for (int ni = 0; ni < 4; ++ni) {
            int ch = wn + ni * 16 + lr;
            float bv = bias[nt * 128 + ch];
            int hh = ch >> 5, d = ch & 31;
#pragma unroll
            for (int r = 0; r < 4; ++r) {
                int tok = tok0 + mi * 16 + lg * 4 + r;
                float val = (acc[mi][ni][r] + bv) * qscale;
                outbuf[((b * HH + hh) * NN + tok) * HD + d] = f2bf(val);
            }
        }
}

// ---------------- Kernel 3: V -> Vt (d-major) ----------------
__global__ __launch_bounds__(256) void v_transpose(const u16* __restrict__ Vb,
                                                   u16* __restrict__ Vtb) {
    __shared__ u16 tile[32][65];
    int bh = blockIdx.y;
    int i0 = blockIdx.x * 64;
    int t = threadIdx.x;
    {
        uint4 val = *(const uint4*)(Vb + (bh * NN + i0) * HD + t * 8);
        int row = t >> 2, d8 = (t & 3) * 8;
        u16 tmp[8]; *(uint4*)tmp = val;
#pragma unroll
        for (int j = 0; j < 8; ++j) tile[d8 + j][row] = tmp[j];
    }
    __syncthreads();
    {
        int d = t >> 3, i8 = (t & 7) * 8;
        u16 tmp[8];
#pragma unroll
        for (int j = 0; j < 8; ++j) tmp[j] = tile[d][i8 + j];
        *(uint4*)(Vtb + (bh * HD + d) * NN + i0 + i8) = *(uint4*)tmp;
    }
}

// ---------------- Kernel 4: flash attention + flat residual ----------------
__global__ __launch_bounds__(256, 2) void attn_kernel(const u16* __restrict__ Qb,
                                                      const u16* __restrict__ Kb,
                                                      const u16* __restrict__ Vtb,
                                                      const float* __restrict__ x,
                                                      float* __restrict__ out) {
    __shared__ u16 Kl[64][40];       // stride 80B: 2-way max on b128 reads
    __shared__ u16 Vl[32][72];       // stride 144B
    __shared__ u16 Pl[4][32][72];    // per-wave P
    int qt = blockIdx.x;     // 0..31
    int bh = blockIdx.y;     // 0..15
    int t = threadIdx.x, w = t >> 6, l = t & 63;
    int lr = l & 15, lg = l >> 4;
    int q0 = qt * 128 + w * 32;

    // hoist Q into registers (reused across all kv tiles)
    bf16x8 qa[2];
#pragma unroll
    for (int qf = 0; qf < 2; ++qf)
        qa[qf] = *(const bf16x8*)(Qb + (bh * NN + q0 + qf * 16 + lr) * HD + lg * 8);

    f32x4 acc[2][2];
    float mst[2][4], lst[2][4];
#pragma unroll
    for (int qf = 0; qf < 2; ++qf) {
#pragma unroll
        for (int dt = 0; dt < 2; ++dt) acc[qf][dt] = f32x4{0.f, 0.f, 0.f, 0.f};
#pragma unroll
        for (int r = 0; r < 4; ++r) { mst[qf][r] = -1e30f; lst[qf][r] = 0.f; }
    }

    const float L2E = 1.44269504f;
    for (int kt = 0; kt < 64; ++kt) {
        int kv0 = kt * 64;
        __syncthreads();
        {   // stage K tile (64x32) and Vt tile (32x64)
            uint4 kv_ = *(const uint4*)(Kb + (bh * NN + kv0) * HD + t * 8);
            *(uint4*)(&Kl[t >> 2][(t & 3) * 8]) = kv_;
            uint4 vv = *(const uint4*)(Vtb + (bh * HD + (t >> 3)) * NN + kv0 + (t & 7) * 8);
            *(uint4*)(&Vl[t >> 3][(t & 7) * 8]) = vv;
        }
        __syncthreads();

        // S = Q * K^T  (scale folded into Q)
        f32x4 s[2][4];
        {
            bf16x8 kb[4];
#pragma unroll
            for (int kvf = 0; kvf < 4; ++kvf)
                kb[kvf] = *(const bf16x8*)(&Kl[kvf * 16 + lr][lg * 8]);
#pragma unroll
            for (int qf = 0; qf < 2; ++qf)
#pragma unroll
                for (int kvf = 0; kvf < 4; ++kvf)
                    s[qf][kvf] = __builtin_amdgcn_mfma_f32_16x16x32_bf16(qa[qf], kb[kvf], f32x4{0.f,0.f,0.f,0.f}, 0, 0, 0);
        }

        // online softmax (rows live in lane groups; reduce over lr via shfl_xor)
#pragma unroll
        for (int qf = 0; qf < 2; ++qf) {
            float alpha[4];
#pragma unroll
            for (int r = 0; r < 4; ++r) {
                float rm = fmaxf(fmaxf(s[qf][0][r], s[qf][1][r]), fmaxf(s[qf][2][r], s[qf][3][r]));
                rm = fmaxf(rm, __shfl_xor(rm, 1));
                rm = fmaxf(rm, __shfl_xor(rm, 2));
                rm = fmaxf(rm, __shfl_xor(rm, 4));
                rm = fmaxf(rm, __shfl_xor(rm, 8));
                float mnew = fmaxf(mst[qf][r], rm);
                alpha[r] = exp2f((mst[qf][r] - mnew) * L2E);
                mst[qf][r] = mnew;
                float ssum = 0.f;
#pragma unroll
                for (int kvf = 0; kvf < 4; ++kvf) {
                    float p = exp2f((s[qf][kvf][r] - mnew) * L2E);
                    s[qf][kvf][r] = p;
                    ssum += p;
                }
                ssum += __shfl_xor(ssum, 1);
                ssum += __shfl_xor(ssum, 2);
                ssum += __shfl_xor(ssum, 4);
                ssum += __shfl_xor(ssum, 8);
                lst[qf][r] = lst[qf][r] * alpha[r] + ssum;
            }
#pragma unroll
            for (int dt = 0; dt < 2; ++dt)
#pragma unroll
                for (int r = 0; r < 4; ++r)
                    acc[qf][dt][r] *= alpha[r];
            // P -> LDS (re-layout D-frag -> A-frag)
#pragma unroll
            for (int kvf = 0; kvf < 4; ++kvf)
#pragma unroll
                for (int r = 0; r < 4; ++r)
                    Pl[w][qf * 16 + lg * 4 + r][kvf * 16 + lr] = f2bf(s[qf][kvf][r]);
        }

        // PV
#pragma unroll
        for (int ks = 0; ks < 2; ++ks) {
            bf16x8 pa[2], vb[2];
#pragma unroll
            for (int qf = 0; qf < 2; ++qf)
                pa[qf] = *(const bf16x8*)(&Pl[w][qf * 16 + lr][ks * 32 + lg * 8]);
#pragma unroll
            for (int dt = 0; dt < 2; ++dt)
                vb[dt] = *(const bf16x8*)(&Vl[dt * 16 + lr][ks * 32 + lg * 8]);
#pragma unroll
            for (int qf = 0; qf < 2; ++qf)
#pragma unroll
                for (int dt = 0; dt < 2; ++dt)
                    acc[qf][dt] = __builtin_amdgcn_mfma_f32_16x16x32_bf16(pa[qf], vb[dt], acc[qf][dt], 0, 0, 0);
        }
    }

    // epilogue: /l  + flat residual add
    int b = bh >> 2, hh = bh & 3;
#pragma unroll
    for (int qf = 0; qf < 2; ++qf)
#pragma unroll
        for (int dt = 0; dt < 2; ++dt)
#pragma unroll
            for (int r = 0; r < 4; ++r) {
                int tok = q0 + qf * 16 + lg * 4 + r;
                int ch = hh * 32 + dt * 16 + lr;
                int g = (b * NN + tok) * CC + ch;
                out[g] = acc[qf][dt][r] / lst[qf][r] + x[g];
            }
}

// ---------------- launch ----------------
extern "C" void kernel_launch(void* const* d_in, const int* in_sizes, int n_in,
                              void* d_out, int out_size, void* d_ws, size_t ws_size,
                              hipStream_t stream) {
    const float* x   = (const float*)d_in[0];
    const float* W   = (const float*)d_in[1];
    const float* bia = (const float*)d_in[2];
    float* out = (float*)d_out;

    char* ws = (char*)d_ws;
    size_t off = 0;
    u16* t_bf  = (u16*)(ws + off); off += (size_t)NTOK * CC * 2;          // 4 MB
    u16* Wt_bf = (u16*)(ws + off); off += (size_t)384 * 128 * 2;          // 96 KB
    u16* Qb    = (u16*)(ws + off); off += (size_t)BB * HH * NN * HD * 2;  // 4 MB
    u16* Kb    = (u16*)(ws + off); off += (size_t)BB * HH * NN * HD * 2;  // 4 MB
    u16* Vb    = (u16*)(ws + off); off += (size_t)BB * HH * NN * HD * 2;  // 4 MB
    u16* Vtb   = (u16*)(ws + off); off += (size_t)BB * HH * NN * HD * 2;  // 4 MB

    hipLaunchKernelGGL(prep_kernel, dim3(524), dim3(256), 0, stream, x, W, t_bf, Wt_bf);
    hipLaunchKernelGGL(qkv_gemm, dim3(128, 3), dim3(256), 0, stream, t_bf, Wt_bf, bia, Qb, Kb, Vb);
    hipLaunchKernelGGL(v_transpose, dim3(64, 16), dim3(256), 0, stream, Vb, Vtb);
    hipLaunchKernelGGL(attn_kernel, dim3(32, 16), dim3(256), 0, stream, Qb, Kb, Vtb, x, out);
}

// Round 3
// 153.342 us; speedup vs baseline: 2.0949x; 2.0949x over previous
//
#include <hip/hip_runtime.h>
#include <hip/hip_bf16.h>

#define BB 4
#define CC 128
#define NN 4096
#define HH 4
#define HD 32
#define NTOK (BB*NN)

typedef float f32x4 __attribute__((ext_vector_type(4)));
typedef short bf16x8 __attribute__((ext_vector_type(8)));
typedef unsigned short u16;
typedef unsigned int u32;

__device__ __forceinline__ u16 f2bf(float f) {
    union { float f; u32 u; } v; v.f = f;
    u32 r = v.u + 0x7FFF + ((v.u >> 16) & 1);
    return (u16)(r >> 16);
}

__device__ __forceinline__ u32 cvtpk(float lo, float hi) {
    u32 r;
    asm("v_cvt_pk_bf16_f32 %0, %1, %2" : "=v"(r) : "v"(lo), "v"(hi));
    return r;
}

// ---------------- Kernel 1: transposes (x -> t_bf token-major, W -> Wt) ----------------
__global__ __launch_bounds__(256) void prep_kernel(const float* __restrict__ x,
                                                   const float* __restrict__ W,
                                                   u16* __restrict__ t_bf,
                                                   u16* __restrict__ Wt_bf) {
    __shared__ u16 tile[64][65];
    int blk = blockIdx.x;
    const float* src; u16* dst; int src_cols, dst_cols, r0, c0;
    if (blk < 512) {
        int b  = blk >> 7;
        int rem = blk & 127;
        int ct = rem >> 6;
        int nt = rem & 63;
        src = x + b * CC * NN;  src_cols = NN; r0 = ct * 64; c0 = nt * 64;
        dst = t_bf + b * NN * CC; dst_cols = CC;
    } else {
        int rem = blk - 512;
        int kt = rem / 6, nt = rem % 6;
        src = W; src_cols = 3 * CC; r0 = kt * 64; c0 = nt * 64;
        dst = Wt_bf; dst_cols = CC;
    }
    int t = threadIdx.x;
#pragma unroll
    for (int p = 0; p < 16; ++p) {
        int rl = p * 4 + (t >> 6);
        int cl = t & 63;
        tile[rl][cl] = f2bf(src[(r0 + rl) * src_cols + c0 + cl]);
    }
    __syncthreads();
#pragma unroll
    for (int p = 0; p < 16; ++p) {
        int cl = p * 4 + (t >> 6);
        int rl = t & 63;
        dst[(c0 + cl) * dst_cols + r0 + rl] = tile[rl][cl];
    }
}

// ---------------- Kernel 2: QKV GEMM (M=16384, N=384, K=128) ----------------
__global__ __launch_bounds__(256, 2) void qkv_gemm(const u16* __restrict__ t_bf,
                                                   const u16* __restrict__ Wt_bf,
                                                   const float* __restrict__ bias,
                                                   u16* __restrict__ Qb,
                                                   u16* __restrict__ Kb,
                                                   u16* __restrict__ Vb) {
    __shared__ u16 Al[128 * 128];
    __shared__ u16 Bl[128 * 128];
    int mt = blockIdx.x;
    int nt = blockIdx.y;
    int t = threadIdx.x;

    {
        const uint4* srcA = (const uint4*)(t_bf + mt * 128 * 128);
        const uint4* srcB = (const uint4*)(Wt_bf + nt * 128 * 128);
#pragma unroll
        for (int p = 0; p < 8; ++p) {
            int cid = p * 256 + t;
            int row = cid >> 4, c16 = cid & 15;
            int sw = (c16 ^ (row & 7)) * 8;
            *(uint4*)(Al + row * 128 + sw) = srcA[cid];
            *(uint4*)(Bl + row * 128 + sw) = srcB[cid];
        }
    }
    __syncthreads();

    int w = t >> 6, l = t & 63;
    int wq = (w >> 1) * 64, wn = (w & 1) * 64;
    int lr = l & 15, lg = l >> 4;

    f32x4 acc[4][4];
#pragma unroll
    for (int mi = 0; mi < 4; ++mi)
#pragma unroll
        for (int ni = 0; ni < 4; ++ni)
            acc[mi][ni] = f32x4{0.f, 0.f, 0.f, 0.f};

#pragma unroll
    for (int kk = 0; kk < 4; ++kk) {
        bf16x8 a[4], bb[4];
        int c = kk * 4 + lg;
#pragma unroll
        for (int mi = 0; mi < 4; ++mi) {
            int R = wq + mi * 16 + lr;
            a[mi] = *(const bf16x8*)(Al + R * 128 + ((c ^ (R & 7)) * 8));
        }
#pragma unroll
        for (int ni = 0; ni < 4; ++ni) {
            int R = wn + ni * 16 + lr;
            bb[ni] = *(const bf16x8*)(Bl + R * 128 + ((c ^ (R & 7)) * 8));
        }
#pragma unroll
        for (int mi = 0; mi < 4; ++mi)
#pragma unroll
            for (int ni = 0; ni < 4; ++ni)
                acc[mi][ni] = __builtin_amdgcn_mfma_f32_16x16x32_bf16(a[mi], bb[ni], acc[mi][ni], 0, 0, 0);
    }

    int b = mt >> 5;
    int tok0 = (mt & 31) * 128 + wq;
    u16* outbuf = (nt == 0) ? Qb : (nt == 1 ? Kb : Vb);
    float qscale = (nt == 0) ? 0.17677669529663687f : 1.0f;
#pragma unroll
    for (int mi = 0; mi < 4; ++mi)
#pragma unroll
        for (int ni = 0; ni < 4; ++ni) {
            int ch = wn + ni * 16 + lr;
            float bv = bias[nt * 128 + ch];
            int hh = ch >> 5, d = ch & 31;
#pragma unroll
            for (int r = 0; r < 4; ++r) {
                int tok = tok0 + mi * 16 + lg * 4 + r;
                float val = (acc[mi][ni][r] + bv) * qscale;
                outbuf[((b * HH + hh) * NN + tok) * HD + d] = f2bf(val);
            }
        }
}

// ---------------- Kernel 3: V -> Vt (d-major) ----------------
__global__ __launch_bounds__(256) void v_transpose(const u16* __restrict__ Vb,
                                                   u16* __restrict__ Vtb) {
    __shared__ u16 tile[32][65];
    int bh = blockIdx.y;
    int i0 = blockIdx.x * 64;
    int t = threadIdx.x;
    {
        uint4 val = *(const uint4*)(Vb + (bh * NN + i0) * HD + t * 8);
        int row = t >> 2, d8 = (t & 3) * 8;
        u16 tmp[8]; *(uint4*)tmp = val;
#pragma unroll
        for (int j = 0; j < 8; ++j) tile[d8 + j][row] = tmp[j];
    }
    __syncthreads();
    {
        int d = t >> 3, i8 = (t & 7) * 8;
        u16 tmp[8];
#pragma unroll
        for (int j = 0; j < 8; ++j) tmp[j] = tile[d][i8 + j];
        *(uint4*)(Vtb + (bh * HD + d) * NN + i0 + i8) = *(uint4*)tmp;
    }
}

// ---------------- Kernel 4: flash attention (swapped-operand), 8 waves ----------------
// S^T = mfma(K, Q): lane (lr,lg) gets S^T[kv=16f+4lg+r][q=lr] -> softmax state per-lane.
// PV: O^T = mfma(Vt, P) with identical k-permutation pi(k)=16*((k>>2)&1)+4*(k>>3)+(k&3)
// applied to both operands; P stays in registers (cvt_pk pack), no LDS round-trip.
// Single-buffer, 2 barriers per kv-tile; global loads issued before barrier 1.
__global__ __launch_bounds__(512, 4) void attn_kernel(const u16* __restrict__ Qb,
                                                      const u16* __restrict__ Kb,
                                                      const u16* __restrict__ Vtb,
                                                      const float* __restrict__ x,
                                                      float* __restrict__ out) {
    __shared__ __align__(16) u16 smem[8192];   // 16KB: K 4KB + V 4KB; epilogue reuses all 16KB
    u16* KL = smem;          // [64][32] linear
    u16* VL = smem + 2048;   // [32][64], 8B-chunk XOR swizzled by (d&15)

    int tid = threadIdx.x;
    int w = tid >> 6, l = tid & 63;
    int lr = l & 15, lg = l >> 4;
    int bh = blockIdx.y, b = bh >> 2, hh = bh & 3;
    int q0w = blockIdx.x * 128 + w * 16;

    // Q fragment (B operand; q = lr, k(d) = 8*lg + e) — reused across all kv tiles
    bf16x8 qa = *(const bf16x8*)(Qb + ((size_t)bh * NN + q0w + lr) * HD + lg * 8);

    // staging: each thread 8B of K and 8B of V per tile
    int kRow = tid >> 3, kOff = (tid & 7) * 4;
    const u16* gK = Kb + ((size_t)bh * NN + kRow) * HD + kOff;
    u16* kDst = KL + kRow * 32 + kOff;
    int vD = tid >> 4, vC8 = tid & 15;
    const u16* gV = Vtb + ((size_t)bh * HD + vD) * NN + vC8 * 4;
    u16* vDst = VL + vD * 64 + ((vC8 ^ (vD & 15)) * 4);

    f32x4 acc0 = {0.f,0.f,0.f,0.f}, acc1 = {0.f,0.f,0.f,0.f};
    float m = -1e30f, ll = 0.f;
    const float L2E = 1.44269504f;
    union PB { u32 w4[4]; bf16x8 v; };

    for (int kt = 0; kt < 64; ++kt) {
        uint2 kreg = *(const uint2*)(gK + kt * 64 * HD);
        uint2 vreg = *(const uint2*)(gV + kt * 64);
        __syncthreads();                 // previous tile's readers done
        *(uint2*)kDst = kreg;
        *(uint2*)vDst = vreg;
        __syncthreads();                 // staging visible

        // ---- S^T = K x Q^T ----
        bf16x8 ka0 = *(const bf16x8*)(KL + (lr     ) * 32 + lg * 8);
        bf16x8 ka1 = *(const bf16x8*)(KL + (16 + lr) * 32 + lg * 8);
        bf16x8 ka2 = *(const bf16x8*)(KL + (32 + lr) * 32 + lg * 8);
        bf16x8 ka3 = *(const bf16x8*)(KL + (48 + lr) * 32 + lg * 8);
        f32x4 z = {0.f,0.f,0.f,0.f};
        f32x4 s0 = __builtin_amdgcn_mfma_f32_16x16x32_bf16(ka0, qa, z, 0, 0, 0);
        f32x4 s1 = __builtin_amdgcn_mfma_f32_16x16x32_bf16(ka1, qa, z, 0, 0, 0);
        f32x4 s2 = __builtin_amdgcn_mfma_f32_16x16x32_bf16(ka2, qa, z, 0, 0, 0);
        f32x4 s3 = __builtin_amdgcn_mfma_f32_16x16x32_bf16(ka3, qa, z, 0, 0, 0);

        // ---- online softmax, unconditional rescale, per-lane state (q = lr) ----
        float t0 = fmaxf(fmaxf(s0[0], s0[1]), fmaxf(s0[2], s0[3]));
        float t1 = fmaxf(fmaxf(s1[0], s1[1]), fmaxf(s1[2], s1[3]));
        float t2 = fmaxf(fmaxf(s2[0], s2[1]), fmaxf(s2[2], s2[3]));
        float t3 = fmaxf(fmaxf(s3[0], s3[1]), fmaxf(s3[2], s3[3]));
        float pmax = fmaxf(fmaxf(t0, t1), fmaxf(t2, t3));
        pmax = fmaxf(pmax, __shfl_xor(pmax, 16));
        pmax = fmaxf(pmax, __shfl_xor(pmax, 32));
        float mnew = fmaxf(m, pmax);
        float alpha = __builtin_amdgcn_exp2f((m - mnew) * L2E);
        m = mnew;
        float mm = m * L2E;
#define EXPX(vv) vv = __builtin_amdgcn_exp2f(__builtin_fmaf(vv, L2E, -mm))
        EXPX(s0[0]); EXPX(s0[1]); EXPX(s0[2]); EXPX(s0[3]);
        EXPX(s1[0]); EXPX(s1[1]); EXPX(s1[2]); EXPX(s1[3]);
        EXPX(s2[0]); EXPX(s2[1]); EXPX(s2[2]); EXPX(s2[3]);
        EXPX(s3[0]); EXPX(s3[1]); EXPX(s3[2]); EXPX(s3[3]);
#undef EXPX
        float psum = ((s0[0] + s0[1]) + (s0[2] + s0[3]))
                   + ((s1[0] + s1[1]) + (s1[2] + s1[3]))
                   + ((s2[0] + s2[1]) + (s2[2] + s2[3]))
                   + ((s3[0] + s3[1]) + (s3[2] + s3[3]));
        psum += __shfl_xor(psum, 16);
        psum += __shfl_xor(psum, 32);
        ll = ll * alpha + psum;
        acc0 *= alpha; acc1 *= alpha;

        // pack P to bf16 B-fragments (k-permuted order; in-register)
        PB p0, p1;
        p0.w4[0] = cvtpk(s0[0], s0[1]); p0.w4[1] = cvtpk(s0[2], s0[3]);
        p0.w4[2] = cvtpk(s1[0], s1[1]); p0.w4[3] = cvtpk(s1[2], s1[3]);
        p1.w4[0] = cvtpk(s2[0], s2[1]); p1.w4[1] = cvtpk(s2[2], s2[3]);
        p1.w4[2] = cvtpk(s3[0], s3[1]); p1.w4[3] = cvtpk(s3[2], s3[3]);

        // ---- PV: O^T += Vt x P (A = Vt fragment with same k-permutation) ----
#pragma unroll
        for (int dt = 0; dt < 2; ++dt) {
            int dd = dt * 16 + lr;
#pragma unroll
            for (int ks = 0; ks < 2; ++ks) {
                uint2 a0 = *(const uint2*)(VL + dd * 64 + ((ks * 8 + lg)     ^ lr) * 4);
                uint2 a1 = *(const uint2*)(VL + dd * 64 + ((ks * 8 + 4 + lg) ^ lr) * 4);
                PB va;
                va.w4[0] = a0.x; va.w4[1] = a0.y; va.w4[2] = a1.x; va.w4[3] = a1.y;
                f32x4& ac = dt ? acc1 : acc0;
                ac = __builtin_amdgcn_mfma_f32_16x16x32_bf16(va.v, (ks ? p1 : p0).v, ac, 0, 0, 0);
            }
        }
    }
    __syncthreads();   // all tile readers done before smem reuse

    // ---- epilogue: normalize, per-wave LDS transpose, coalesced f32 store + flat residual ----
    float inv = 1.0f / ll;
    acc0 *= inv; acc1 *= inv;

    float* OW = (float*)smem + w * 512;   // per-wave 16q x 32d tile, 16B-chunk swizzle ^(q&7)
    *(f32x4*)(OW + lr * 32 + ((lg    ) ^ (lr & 7)) * 4) = acc0;   // d chunk lg
    *(f32x4*)(OW + lr * 32 + ((4 + lg) ^ (lr & 7)) * 4) = acc1;   // d chunk 4+lg
    int q = l & 15, part = l >> 4;
    f32x4 r0 = *(const f32x4*)(OW + q * 32 + ((2 * part    ) ^ (q & 7)) * 4);
    f32x4 r1 = *(const f32x4*)(OW + q * 32 + ((2 * part + 1) ^ (q & 7)) * 4);

    size_t gbase = ((size_t)b * NN + q0w + q) * CC + hh * 32 + part * 8;
    f32x4 x0 = *(const f32x4*)(x + gbase);
    f32x4 x1 = *(const f32x4*)(x + gbase + 4);
    *(f32x4*)(out + gbase)     = r0 + x0;
    *(f32x4*)(out + gbase + 4) = r1 + x1;
}

// ---------------- launch ----------------
extern "C" void kernel_launch(void* const* d_in, const int* in_sizes, int n_in,
                              void* d_out, int out_size, void* d_ws, size_t ws_size,
                              hipStream_t stream) {
    const float* x   = (const float*)d_in[0];
    const float* W   = (const float*)d_in[1];
    const float* bia = (const float*)d_in[2];
    float* out = (float*)d_out;

    char* ws = (char*)d_ws;
    size_t off = 0;
    u16* t_bf  = (u16*)(ws + off); off += (size_t)NTOK * CC * 2;
    u16* Wt_bf = (u16*)(ws + off); off += (size_t)384 * 128 * 2;
    u16* Qb    = (u16*)(ws + off); off += (size_t)BB * HH * NN * HD * 2;
    u16* Kb    = (u16*)(ws + off); off += (size_t)BB * HH * NN * HD * 2;
    u16* Vb    = (u16*)(ws + off); off += (size_t)BB * HH * NN * HD * 2;
    u16* Vtb   = (u16*)(ws + off); off += (size_t)BB * HH * NN * HD * 2;

    hipLaunchKernelGGL(prep_kernel, dim3(524), dim3(256), 0, stream, x, W, t_bf, Wt_bf);
    hipLaunchKernelGGL(qkv_gemm, dim3(128, 3), dim3(256), 0, stream, t_bf, Wt_bf, bia, Qb, Kb, Vb);
    hipLaunchKernelGGL(v_transpose, dim3(64, 16), dim3(256), 0, stream, Vb, Vtb);
    hipLaunchKernelGGL(attn_kernel, dim3(32, 16), dim3(512), 0, stream, Qb, Kb, Vtb, x, out);
}

// Round 8
// 149.119 us; speedup vs baseline: 2.1543x; 1.0283x over previous
//
#include <hip/hip_runtime.h>
#include <hip/hip_bf16.h>

#define BB 4
#define CC 128
#define NN 4096
#define HH 4
#define HD 32
#define NTOK (BB*NN)

typedef float f32x4 __attribute__((ext_vector_type(4)));
typedef short bf16x8 __attribute__((ext_vector_type(8)));
typedef unsigned short u16;
typedef unsigned int u32;

__device__ __forceinline__ u16 f2bf(float f) {
    union { float f; u32 u; } v; v.f = f;
    u32 r = v.u + 0x7FFF + ((v.u >> 16) & 1);
    return (u16)(r >> 16);
}

__device__ __forceinline__ u32 cvtpk(float lo, float hi) {
    u32 r;
    asm("v_cvt_pk_bf16_f32 %0, %1, %2" : "=v"(r) : "v"(lo), "v"(hi));
    return r;
}

// ---------------- Kernel 1: transposes (x -> t_bf token-major, W -> Wt) ----------------
__global__ __launch_bounds__(256) void prep_kernel(const float* __restrict__ x,
                                                   const float* __restrict__ W,
                                                   u16* __restrict__ t_bf,
                                                   u16* __restrict__ Wt_bf) {
    __shared__ u16 tile[64][65];
    int blk = blockIdx.x;
    const float* src; u16* dst; int src_cols, dst_cols, r0, c0;
    if (blk < 512) {
        int b  = blk >> 7;
        int rem = blk & 127;
        int ct = rem >> 6;
        int nt = rem & 63;
        src = x + b * CC * NN;  src_cols = NN; r0 = ct * 64; c0 = nt * 64;
        dst = t_bf + b * NN * CC; dst_cols = CC;
    } else {
        int rem = blk - 512;
        int kt = rem / 6, nt = rem % 6;
        src = W; src_cols = 3 * CC; r0 = kt * 64; c0 = nt * 64;
        dst = Wt_bf; dst_cols = CC;
    }
    int t = threadIdx.x;
#pragma unroll
    for (int p = 0; p < 16; ++p) {
        int rl = p * 4 + (t >> 6);
        int cl = t & 63;
        tile[rl][cl] = f2bf(src[(r0 + rl) * src_cols + c0 + cl]);
    }
    __syncthreads();
#pragma unroll
    for (int p = 0; p < 16; ++p) {
        int cl = p * 4 + (t >> 6);
        int rl = t & 63;
        dst[(c0 + cl) * dst_cols + r0 + rl] = tile[rl][cl];
    }
}

// ---------------- Kernel 2: QKV GEMM (M=16384, N=384, K=128); V stored transposed ----------------
__global__ __launch_bounds__(256, 2) void qkv_gemm(const u16* __restrict__ t_bf,
                                                   const u16* __restrict__ Wt_bf,
                                                   const float* __restrict__ bias,
                                                   u16* __restrict__ Qb,
                                                   u16* __restrict__ Kb,
                                                   u16* __restrict__ Vtb) {
    __shared__ u16 Al[128 * 128];
    __shared__ u16 Bl[128 * 128];
    int mt = blockIdx.x;
    int nt = blockIdx.y;
    int t = threadIdx.x;

    {
        const uint4* srcA = (const uint4*)(t_bf + mt * 128 * 128);
        const uint4* srcB = (const uint4*)(Wt_bf + nt * 128 * 128);
#pragma unroll
        for (int p = 0; p < 8; ++p) {
            int cid = p * 256 + t;
            int row = cid >> 4, c16 = cid & 15;
            int sw = (c16 ^ (row & 7)) * 8;
            *(uint4*)(Al + row * 128 + sw) = srcA[cid];
            *(uint4*)(Bl + row * 128 + sw) = srcB[cid];
        }
    }
    __syncthreads();

    int w = t >> 6, l = t & 63;
    int wq = (w >> 1) * 64, wn = (w & 1) * 64;
    int lr = l & 15, lg = l >> 4;

    f32x4 acc[4][4];
#pragma unroll
    for (int mi = 0; mi < 4; ++mi)
#pragma unroll
        for (int ni = 0; ni < 4; ++ni)
            acc[mi][ni] = f32x4{0.f, 0.f, 0.f, 0.f};

#pragma unroll
    for (int kk = 0; kk < 4; ++kk) {
        bf16x8 a[4], bb[4];
        int c = kk * 4 + lg;
#pragma unroll
        for (int mi = 0; mi < 4; ++mi) {
            int R = wq + mi * 16 + lr;
            a[mi] = *(const bf16x8*)(Al + R * 128 + ((c ^ (R & 7)) * 8));
        }
#pragma unroll
        for (int ni = 0; ni < 4; ++ni) {
            int R = wn + ni * 16 + lr;
            bb[ni] = *(const bf16x8*)(Bl + R * 128 + ((c ^ (R & 7)) * 8));
        }
#pragma unroll
        for (int mi = 0; mi < 4; ++mi)
#pragma unroll
            for (int ni = 0; ni < 4; ++ni)
                acc[mi][ni] = __builtin_amdgcn_mfma_f32_16x16x32_bf16(a[mi], bb[ni], acc[mi][ni], 0, 0, 0);
    }

    int b = mt >> 5;
    int tok0 = (mt & 31) * 128 + wq;
    if (nt == 2) {
        // V: store directly transposed [bh][d][n] — lane already holds 4 consecutive
        // tokens (lg*4+r) at fixed channel lr -> one 8B store per (mi,ni).
#pragma unroll
        for (int mi = 0; mi < 4; ++mi)
#pragma unroll
            for (int ni = 0; ni < 4; ++ni) {
                int ch = wn + ni * 16 + lr;
                float bv = bias[256 + ch];
                int hh = ch >> 5, d = ch & 31;
                int tok = tok0 + mi * 16 + lg * 4;
                u16 tmp[4];
#pragma unroll
                for (int r = 0; r < 4; ++r) tmp[r] = f2bf(acc[mi][ni][r] + bv);
                *(uint2*)(Vtb + ((size_t)(b * HH + hh) * HD + d) * NN + tok) = *(uint2*)tmp;
            }
    } else {
        u16* outbuf = (nt == 0) ? Qb : Kb;
        float qscale = (nt == 0) ? 0.17677669529663687f : 1.0f;
#pragma unroll
        for (int mi = 0; mi < 4; ++mi)
#pragma unroll
            for (int ni = 0; ni < 4; ++ni) {
                int ch = wn + ni * 16 + lr;
                float bv = bias[nt * 128 + ch];
                int hh = ch >> 5, d = ch & 31;
#pragma unroll
                for (int r = 0; r < 4; ++r) {
                    int tok = tok0 + mi * 16 + lg * 4 + r;
                    float val = (acc[mi][ni][r] + bv) * qscale;
                    outbuf[((b * HH + hh) * NN + tok) * HD + d] = f2bf(val);
                }
            }
    }
}

// ---------------- Kernel 3: flash attention (swapped-operand), 8 waves ----------------
// ROUND-3 PASSING KERNEL VERBATIM (single LDS buffer, loads at top of consuming
// iteration, 2 barriers/tile). Only change: grid decode swapped (bh = blockIdx.x,
// qt = blockIdx.y) so linear block id = bh + 16*qt -> with round-robin dispatch all
// 32 blocks of one head land on XCD bh%8 (2 heads/XCD, 2MB KV in 4MB L2).
__global__ __launch_bounds__(512, 4) void attn_kernel(const u16* __restrict__ Qb,
                                                      const u16* __restrict__ Kb,
                                                      const u16* __restrict__ Vtb,
                                                      const float* __restrict__ x,
                                                      float* __restrict__ out) {
    __shared__ __align__(16) u16 smem[8192];   // K[64][32]=4KB + V[32][64]=4KB; epilogue reuses 16KB
    u16* KL = smem;
    u16* VL = smem + 2048;

    int tid = threadIdx.x;
    int w = tid >> 6, l = tid & 63;
    int lr = l & 15, lg = l >> 4;
    int bh = blockIdx.x;   // 0..15 (fast dim -> XCD affinity)
    int qt = blockIdx.y;   // 0..31
    int b = bh >> 2, hh = bh & 3;
    int q0w = qt * 128 + w * 16;

    // Q fragment (B operand; q = lr, k(d) = 8*lg + e) — reused across all kv tiles
    bf16x8 qa = *(const bf16x8*)(Qb + ((size_t)bh * NN + q0w + lr) * HD + lg * 8);

    // staging: each thread 8B of K and 8B of V per tile
    int kRow = tid >> 3, kOff = (tid & 7) * 4;
    const u16* gK = Kb + ((size_t)bh * NN + kRow) * HD + kOff;
    u16* kDst = KL + kRow * 32 + kOff;
    int vD = tid >> 4, vC8 = tid & 15;
    const u16* gV = Vtb + ((size_t)bh * HD + vD) * NN + vC8 * 4;
    u16* vDst = VL + vD * 64 + ((vC8 ^ (vD & 15)) * 4);

    f32x4 acc0 = {0.f,0.f,0.f,0.f}, acc1 = {0.f,0.f,0.f,0.f};
    float m = -1e30f, ll = 0.f;
    const float L2E = 1.44269504f;
    union PB { u32 w4[4]; bf16x8 v; };

    for (int kt = 0; kt < 64; ++kt) {
        uint2 kreg = *(const uint2*)(gK + (size_t)kt * 64 * HD);
        uint2 vreg = *(const uint2*)(gV + kt * 64);
        __syncthreads();                 // (A) previous tile's readers done
        *(uint2*)kDst = kreg;
        *(uint2*)vDst = vreg;
        __syncthreads();                 // (B) staging visible

        // ---- S^T = K x Q^T ----
        bf16x8 ka0 = *(const bf16x8*)(KL + (lr     ) * 32 + lg * 8);
        bf16x8 ka1 = *(const bf16x8*)(KL + (16 + lr) * 32 + lg * 8);
        bf16x8 ka2 = *(const bf16x8*)(KL + (32 + lr) * 32 + lg * 8);
        bf16x8 ka3 = *(const bf16x8*)(KL + (48 + lr) * 32 + lg * 8);
        f32x4 z = {0.f,0.f,0.f,0.f};
        f32x4 s0 = __builtin_amdgcn_mfma_f32_16x16x32_bf16(ka0, qa, z, 0, 0, 0);
        f32x4 s1 = __builtin_amdgcn_mfma_f32_16x16x32_bf16(ka1, qa, z, 0, 0, 0);
        f32x4 s2 = __builtin_amdgcn_mfma_f32_16x16x32_bf16(ka2, qa, z, 0, 0, 0);
        f32x4 s3 = __builtin_amdgcn_mfma_f32_16x16x32_bf16(ka3, qa, z, 0, 0, 0);

        // ---- online softmax, unconditional rescale, per-lane state (q = lr) ----
        float t0 = fmaxf(fmaxf(s0[0], s0[1]), fmaxf(s0[2], s0[3]));
        float t1 = fmaxf(fmaxf(s1[0], s1[1]), fmaxf(s1[2], s1[3]));
        float t2 = fmaxf(fmaxf(s2[0], s2[1]), fmaxf(s2[2], s2[3]));
        float t3 = fmaxf(fmaxf(s3[0], s3[1]), fmaxf(s3[2], s3[3]));
        float pmax = fmaxf(fmaxf(t0, t1), fmaxf(t2, t3));
        pmax = fmaxf(pmax, __shfl_xor(pmax, 16));
        pmax = fmaxf(pmax, __shfl_xor(pmax, 32));
        float mnew = fmaxf(m, pmax);
        float alpha = __builtin_amdgcn_exp2f((m - mnew) * L2E);
        m = mnew;
        float mm = m * L2E;
#define EXPX(vv) vv = __builtin_amdgcn_exp2f(__builtin_fmaf(vv, L2E, -mm))
        EXPX(s0[0]); EXPX(s0[1]); EXPX(s0[2]); EXPX(s0[3]);
        EXPX(s1[0]); EXPX(s1[1]); EXPX(s1[2]); EXPX(s1[3]);
        EXPX(s2[0]); EXPX(s2[1]); EXPX(s2[2]); EXPX(s2[3]);
        EXPX(s3[0]); EXPX(s3[1]); EXPX(s3[2]); EXPX(s3[3]);
#undef EXPX
        float psum = ((s0[0] + s0[1]) + (s0[2] + s0[3]))
                   + ((s1[0] + s1[1]) + (s1[2] + s1[3]))
                   + ((s2[0] + s2[1]) + (s2[2] + s2[3]))
                   + ((s3[0] + s3[1]) + (s3[2] + s3[3]));
        psum += __shfl_xor(psum, 16);
        psum += __shfl_xor(psum, 32);
        ll = ll * alpha + psum;
        acc0 *= alpha; acc1 *= alpha;

        // pack P to bf16 B-fragments (k-permuted order; in-register)
        PB p0, p1;
        p0.w4[0] = cvtpk(s0[0], s0[1]); p0.w4[1] = cvtpk(s0[2], s0[3]);
        p0.w4[2] = cvtpk(s1[0], s1[1]); p0.w4[3] = cvtpk(s1[2], s1[3]);
        p1.w4[0] = cvtpk(s2[0], s2[1]); p1.w4[1] = cvtpk(s2[2], s2[3]);
        p1.w4[2] = cvtpk(s3[0], s3[1]); p1.w4[3] = cvtpk(s3[2], s3[3]);

        // ---- PV: O^T += Vt x P (A = Vt fragment with same k-permutation) ----
#pragma unroll
        for (int dt = 0; dt < 2; ++dt) {
            int dd = dt * 16 + lr;
#pragma unroll
            for (int ks = 0; ks < 2; ++ks) {
                uint2 a0 = *(const uint2*)(VL + dd * 64 + ((ks * 8 + lg)     ^ lr) * 4);
                uint2 a1 = *(const uint2*)(VL + dd * 64 + ((ks * 8 + 4 + lg) ^ lr) * 4);
                PB va;
                va.w4[0] = a0.x; va.w4[1] = a0.y; va.w4[2] = a1.x; va.w4[3] = a1.y;
                f32x4& ac = dt ? acc1 : acc0;
                ac = __builtin_amdgcn_mfma_f32_16x16x32_bf16(va.v, (ks ? p1 : p0).v, ac, 0, 0, 0);
            }
        }
    }
    __syncthreads();   // all tile readers done before epilogue smem reuse

    // ---- epilogue: normalize, per-wave LDS transpose, coalesced f32 store + flat residual ----
    float inv = 1.0f / ll;
    acc0 *= inv; acc1 *= inv;

    float* OW = (float*)smem + w * 512;   // per-wave 16q x 32d tile, 16B-chunk swizzle ^(q&7)
    *(f32x4*)(OW + lr * 32 + ((lg    ) ^ (lr & 7)) * 4) = acc0;
    *(f32x4*)(OW + lr * 32 + ((4 + lg) ^ (lr & 7)) * 4) = acc1;
    int q = l & 15, part = l >> 4;
    f32x4 r0 = *(const f32x4*)(OW + q * 32 + ((2 * part    ) ^ (q & 7)) * 4);
    f32x4 r1 = *(const f32x4*)(OW + q * 32 + ((2 * part + 1) ^ (q & 7)) * 4);

    size_t gbase = ((size_t)b * NN + q0w + q) * CC + hh * 32 + part * 8;
    f32x4 x0 = *(const f32x4*)(x + gbase);
    f32x4 x1 = *(const f32x4*)(x + gbase + 4);
    *(f32x4*)(out + gbase)     = r0 + x0;
    *(f32x4*)(out + gbase + 4) = r1 + x1;
}

// ---------------- launch ----------------
extern "C" void kernel_launch(void* const* d_in, const int* in_sizes, int n_in,
                              void* d_out, int out_size, void* d_ws, size_t ws_size,
                              hipStream_t stream) {
    const float* x   = (const float*)d_in[0];
    const float* W   = (const float*)d_in[1];
    const float* bia = (const float*)d_in[2];
    float* out = (float*)d_out;

    char* ws = (char*)d_ws;
    size_t off = 0;
    u16* t_bf  = (u16*)(ws + off); off += (size_t)NTOK * CC * 2;          // 4 MB
    u16* Wt_bf = (u16*)(ws + off); off += (size_t)384 * 128 * 2;          // 96 KB
    u16* Qb    = (u16*)(ws + off); off += (size_t)BB * HH * NN * HD * 2;  // 4 MB
    u16* Kb    = (u16*)(ws + off); off += (size_t)BB * HH * NN * HD * 2;  // 4 MB
    u16* Vtb   = (u16*)(ws + off); off += (size_t)BB * HH * NN * HD * 2;  // 4 MB

    hipLaunchKernelGGL(prep_kernel, dim3(524), dim3(256), 0, stream, x, W, t_bf, Wt_bf);
    hipLaunchKernelGGL(qkv_gemm, dim3(128, 3), dim3(256), 0, stream, t_bf, Wt_bf, bia, Qb, Kb, Vtb);
    hipLaunchKernelGGL(attn_kernel, dim3(16, 32), dim3(512), 0, stream, Qb, Kb, Vtb, x, out);
}

// Round 10
// 147.951 us; speedup vs baseline: 2.1713x; 1.0079x over previous
//
#include <hip/hip_runtime.h>
#include <hip/hip_bf16.h>

#define BB 4
#define CC 128
#define NN 4096
#define HH 4
#define HD 32
#define NTOK (BB*NN)

typedef float f32x4 __attribute__((ext_vector_type(4)));
typedef short bf16x8 __attribute__((ext_vector_type(8)));
typedef unsigned short u16;
typedef unsigned int u32;

__device__ __forceinline__ u16 f2bf(float f) {
    union { float f; u32 u; } v; v.f = f;
    u32 r = v.u + 0x7FFF + ((v.u >> 16) & 1);
    return (u16)(r >> 16);
}

__device__ __forceinline__ u32 cvtpk(float lo, float hi) {
    u32 r;
    asm("v_cvt_pk_bf16_f32 %0, %1, %2" : "=v"(r) : "v"(lo), "v"(hi));
    return r;
}

// ---------------- Kernel 1: transposes (x -> t_bf token-major, W -> Wt) ----------------
__global__ __launch_bounds__(256) void prep_kernel(const float* __restrict__ x,
                                                   const float* __restrict__ W,
                                                   u16* __restrict__ t_bf,
                                                   u16* __restrict__ Wt_bf) {
    __shared__ u16 tile[64][65];
    int blk = blockIdx.x;
    const float* src; u16* dst; int src_cols, dst_cols, r0, c0;
    if (blk < 512) {
        int b  = blk >> 7;
        int rem = blk & 127;
        int ct = rem >> 6;
        int nt = rem & 63;
        src = x + b * CC * NN;  src_cols = NN; r0 = ct * 64; c0 = nt * 64;
        dst = t_bf + b * NN * CC; dst_cols = CC;
    } else {
        int rem = blk - 512;
        int kt = rem / 6, nt = rem % 6;
        src = W; src_cols = 3 * CC; r0 = kt * 64; c0 = nt * 64;
        dst = Wt_bf; dst_cols = CC;
    }
    int t = threadIdx.x;
#pragma unroll
    for (int p = 0; p < 16; ++p) {
        int rl = p * 4 + (t >> 6);
        int cl = t & 63;
        tile[rl][cl] = f2bf(src[(r0 + rl) * src_cols + c0 + cl]);
    }
    __syncthreads();
#pragma unroll
    for (int p = 0; p < 16; ++p) {
        int cl = p * 4 + (t >> 6);
        int rl = t & 63;
        dst[(c0 + cl) * dst_cols + r0 + rl] = tile[rl][cl];
    }
}

// ---------------- Kernel 2: QKV GEMM (M=16384, N=384, K=128); V stored transposed ----------------
__global__ __launch_bounds__(256, 2) void qkv_gemm(const u16* __restrict__ t_bf,
                                                   const u16* __restrict__ Wt_bf,
                                                   const float* __restrict__ bias,
                                                   u16* __restrict__ Qb,
                                                   u16* __restrict__ Kb,
                                                   u16* __restrict__ Vtb) {
    __shared__ u16 Al[128 * 128];
    __shared__ u16 Bl[128 * 128];
    int mt = blockIdx.x;
    int nt = blockIdx.y;
    int t = threadIdx.x;

    {
        const uint4* srcA = (const uint4*)(t_bf + mt * 128 * 128);
        const uint4* srcB = (const uint4*)(Wt_bf + nt * 128 * 128);
#pragma unroll
        for (int p = 0; p < 8; ++p) {
            int cid = p * 256 + t;
            int row = cid >> 4, c16 = cid & 15;
            int sw = (c16 ^ (row & 7)) * 8;
            *(uint4*)(Al + row * 128 + sw) = srcA[cid];
            *(uint4*)(Bl + row * 128 + sw) = srcB[cid];
        }
    }
    __syncthreads();

    int w = t >> 6, l = t & 63;
    int wq = (w >> 1) * 64, wn = (w & 1) * 64;
    int lr = l & 15, lg = l >> 4;

    f32x4 acc[4][4];
#pragma unroll
    for (int mi = 0; mi < 4; ++mi)
#pragma unroll
        for (int ni = 0; ni < 4; ++ni)
            acc[mi][ni] = f32x4{0.f, 0.f, 0.f, 0.f};

#pragma unroll
    for (int kk = 0; kk < 4; ++kk) {
        bf16x8 a[4], bb[4];
        int c = kk * 4 + lg;
#pragma unroll
        for (int mi = 0; mi < 4; ++mi) {
            int R = wq + mi * 16 + lr;
            a[mi] = *(const bf16x8*)(Al + R * 128 + ((c ^ (R & 7)) * 8));
        }
#pragma unroll
        for (int ni = 0; ni < 4; ++ni) {
            int R = wn + ni * 16 + lr;
            bb[ni] = *(const bf16x8*)(Bl + R * 128 + ((c ^ (R & 7)) * 8));
        }
#pragma unroll
        for (int mi = 0; mi < 4; ++mi)
#pragma unroll
            for (int ni = 0; ni < 4; ++ni)
                acc[mi][ni] = __builtin_amdgcn_mfma_f32_16x16x32_bf16(a[mi], bb[ni], acc[mi][ni], 0, 0, 0);
    }

    int b = mt >> 5;
    int tok0 = (mt & 31) * 128 + wq;
    if (nt == 2) {
#pragma unroll
        for (int mi = 0; mi < 4; ++mi)
#pragma unroll
            for (int ni = 0; ni < 4; ++ni) {
                int ch = wn + ni * 16 + lr;
                float bv = bias[256 + ch];
                int hh = ch >> 5, d = ch & 31;
                int tok = tok0 + mi * 16 + lg * 4;
                u16 tmp[4];
#pragma unroll
                for (int r = 0; r < 4; ++r) tmp[r] = f2bf(acc[mi][ni][r] + bv);
                *(uint2*)(Vtb + ((size_t)(b * HH + hh) * HD + d) * NN + tok) = *(uint2*)tmp;
            }
    } else {
        u16* outbuf = (nt == 0) ? Qb : Kb;
        float qscale = (nt == 0) ? 0.17677669529663687f : 1.0f;
#pragma unroll
        for (int mi = 0; mi < 4; ++mi)
#pragma unroll
            for (int ni = 0; ni < 4; ++ni) {
                int ch = wn + ni * 16 + lr;
                float bv = bias[nt * 128 + ch];
                int hh = ch >> 5, d = ch & 31;
#pragma unroll
                for (int r = 0; r < 4; ++r) {
                    int tok = tok0 + mi * 16 + lg * 4 + r;
                    float val = (acc[mi][ni][r] + bv) * qscale;
                    outbuf[((b * HH + hh) * NN + tok) * HD + d] = f2bf(val);
                }
            }
    }
}

// ---------------- Kernel 3: flash attention (swapped-operand), 4 waves, QBLK=32/wave --------
// Round-3/8 sync skeleton VERBATIM: loads at top of consuming iteration, single LDS
// buffer, 2 barriers/tile. Deltas vs round 8 (all math/layout, no sync change):
//  - 2 Q fragments per wave (q0w+lr, q0w+16+lr): K reads / V reads / staging / barriers
//    amortized over 2x elements. 4 waves/block, grid 32x16 (bh fast -> XCD affinity).
//  - K LDS row stride 40 u16 (80B): removes the 64B-stride b128 bank aliasing.
//  - per-lane partial l, cross-lane reduced once in the epilogue (alpha is uniform
//    across the 4 lane-groups of a q column, so the sum commutes).
__global__ __launch_bounds__(256, 2) void attn_kernel(const u16* __restrict__ Qb,
                                                      const u16* __restrict__ Kb,
                                                      const u16* __restrict__ Vtb,
                                                      const float* __restrict__ x,
                                                      float* __restrict__ out) {
    __shared__ __align__(16) u16 smem[7168];   // K[64][40]=5KB + V[32][64]=4KB; epilogue reuses 8KB
    u16* KL = smem;            // row stride 40
    u16* VL = smem + 2560;     // [32][64], 8B-chunk XOR swizzled by (d&15)

    int tid = threadIdx.x;
    int w = tid >> 6, l = tid & 63;
    int lr = l & 15, lg = l >> 4;
    int bh = blockIdx.x;   // 0..15 (fast dim -> XCD affinity)
    int qt = blockIdx.y;   // 0..31
    int b = bh >> 2, hh = bh & 3;
    int q0w = qt * 128 + w * 32;

    // Two Q fragments (B operand; q = lr / 16+lr, k(d) = 8*lg + e)
    bf16x8 qa0 = *(const bf16x8*)(Qb + ((size_t)bh * NN + q0w + lr     ) * HD + lg * 8);
    bf16x8 qa1 = *(const bf16x8*)(Qb + ((size_t)bh * NN + q0w + 16 + lr) * HD + lg * 8);

    // staging: each of 256 threads: 16B of K and 16B of V per tile
    int kRow = tid >> 2, kOff = (tid & 3) * 8;
    const u16* gK = Kb + ((size_t)bh * NN + kRow) * HD + kOff;
    u16* kDst = KL + kRow * 40 + kOff;
    int vD = tid >> 3, vC16 = tid & 7;
    const u16* gV = Vtb + ((size_t)bh * HD + vD) * NN + vC16 * 8;
    u16* vDstA = VL + vD * 64 + (((2 * vC16)     ^ (vD & 15)) * 4);
    u16* vDstB = VL + vD * 64 + (((2 * vC16 + 1) ^ (vD & 15)) * 4);

    f32x4 a00 = {0.f,0.f,0.f,0.f}, a01 = {0.f,0.f,0.f,0.f};
    f32x4 a10 = {0.f,0.f,0.f,0.f}, a11 = {0.f,0.f,0.f,0.f};
    float m0 = -1e30f, ll0 = 0.f, m1 = -1e30f, ll1 = 0.f;
    const float L2E = 1.44269504f;
    union PB { u32 w4[4]; bf16x8 v; };

    for (int kt = 0; kt < 64; ++kt) {
        uint4 kreg = *(const uint4*)(gK + (size_t)kt * 64 * HD);
        uint4 vreg = *(const uint4*)(gV + kt * 64);
        __syncthreads();                 // (A) previous tile's readers done
        *(uint4*)kDst = kreg;
        *(uint2*)vDstA = make_uint2(vreg.x, vreg.y);
        *(uint2*)vDstB = make_uint2(vreg.z, vreg.w);
        __syncthreads();                 // (B) staging visible

        // ---- shared K fragments ----
        bf16x8 ka0 = *(const bf16x8*)(KL + (lr     ) * 40 + lg * 8);
        bf16x8 ka1 = *(const bf16x8*)(KL + (16 + lr) * 40 + lg * 8);
        bf16x8 ka2 = *(const bf16x8*)(KL + (32 + lr) * 40 + lg * 8);
        bf16x8 ka3 = *(const bf16x8*)(KL + (48 + lr) * 40 + lg * 8);
        f32x4 z = {0.f,0.f,0.f,0.f};

        // ---- S^T = K x Q^T, both q-fragments ----
        f32x4 s0 = __builtin_amdgcn_mfma_f32_16x16x32_bf16(ka0, qa0, z, 0, 0, 0);
        f32x4 s1 = __builtin_amdgcn_mfma_f32_16x16x32_bf16(ka1, qa0, z, 0, 0, 0);
        f32x4 s2 = __builtin_amdgcn_mfma_f32_16x16x32_bf16(ka2, qa0, z, 0, 0, 0);
        f32x4 s3 = __builtin_amdgcn_mfma_f32_16x16x32_bf16(ka3, qa0, z, 0, 0, 0);
        f32x4 u0 = __builtin_amdgcn_mfma_f32_16x16x32_bf16(ka0, qa1, z, 0, 0, 0);
        f32x4 u1 = __builtin_amdgcn_mfma_f32_16x16x32_bf16(ka1, qa1, z, 0, 0, 0);
        f32x4 u2 = __builtin_amdgcn_mfma_f32_16x16x32_bf16(ka2, qa1, z, 0, 0, 0);
        f32x4 u3 = __builtin_amdgcn_mfma_f32_16x16x32_bf16(ka3, qa1, z, 0, 0, 0);

#define EXPX(vv, mmv) vv = __builtin_amdgcn_exp2f(__builtin_fmaf(vv, L2E, -mmv))
        // ---- softmax qf0 (per-lane state, q = lr) ----
        PB p0, p1;
        {
            float t0 = fmaxf(fmaxf(s0[0], s0[1]), fmaxf(s0[2], s0[3]));
            float t1 = fmaxf(fmaxf(s1[0], s1[1]), fmaxf(s1[2], s1[3]));
            float t2 = fmaxf(fmaxf(s2[0], s2[1]), fmaxf(s2[2], s2[3]));
            float t3 = fmaxf(fmaxf(s3[0], s3[1]), fmaxf(s3[2], s3[3]));
            float pmax = fmaxf(fmaxf(t0, t1), fmaxf(t2, t3));
            pmax = fmaxf(pmax, __shfl_xor(pmax, 16));
            pmax = fmaxf(pmax, __shfl_xor(pmax, 32));
            float mnew = fmaxf(m0, pmax);
            float alpha = __builtin_amdgcn_exp2f((m0 - mnew) * L2E);
            m0 = mnew;
            float mm = m0 * L2E;
            EXPX(s0[0], mm); EXPX(s0[1], mm); EXPX(s0[2], mm); EXPX(s0[3], mm);
            EXPX(s1[0], mm); EXPX(s1[1], mm); EXPX(s1[2], mm); EXPX(s1[3], mm);
            EXPX(s2[0], mm); EXPX(s2[1], mm); EXPX(s2[2], mm); EXPX(s2[3], mm);
            EXPX(s3[0], mm); EXPX(s3[1], mm); EXPX(s3[2], mm); EXPX(s3[3], mm);
            float psum = ((s0[0] + s0[1]) + (s0[2] + s0[3]))
                       + ((s1[0] + s1[1]) + (s1[2] + s1[3]))
                       + ((s2[0] + s2[1]) + (s2[2] + s2[3]))
                       + ((s3[0] + s3[1]) + (s3[2] + s3[3]));
            ll0 = ll0 * alpha + psum;    // per-lane partial; reduced in epilogue
            a00 *= alpha; a01 *= alpha;
            p0.w4[0] = cvtpk(s0[0], s0[1]); p0.w4[1] = cvtpk(s0[2], s0[3]);
            p0.w4[2] = cvtpk(s1[0], s1[1]); p0.w4[3] = cvtpk(s1[2], s1[3]);
            p1.w4[0] = cvtpk(s2[0], s2[1]); p1.w4[1] = cvtpk(s2[2], s2[3]);
            p1.w4[2] = cvtpk(s3[0], s3[1]); p1.w4[3] = cvtpk(s3[2], s3[3]);
        }
        // ---- softmax qf1 ----
        PB p2, p3;
        {
            float t0 = fmaxf(fmaxf(u0[0], u0[1]), fmaxf(u0[2], u0[3]));
            float t1 = fmaxf(fmaxf(u1[0], u1[1]), fmaxf(u1[2], u1[3]));
            float t2 = fmaxf(fmaxf(u2[0], u2[1]), fmaxf(u2[2], u2[3]));
            float t3 = fmaxf(fmaxf(u3[0], u3[1]), fmaxf(u3[2], u3[3]));
            float pmax = fmaxf(fmaxf(t0, t1), fmaxf(t2, t3));
            pmax = fmaxf(pmax, __shfl_xor(pmax, 16));
            pmax = fmaxf(pmax, __shfl_xor(pmax, 32));
            float mnew = fmaxf(m1, pmax);
            float alpha = __builtin_amdgcn_exp2f((m1 - mnew) * L2E);
            m1 = mnew;
            float mm = m1 * L2E;
            EXPX(u0[0], mm); EXPX(u0[1], mm); EXPX(u0[2], mm); EXPX(u0[3], mm);
            EXPX(u1[0], mm); EXPX(u1[1], mm); EXPX(u1[2], mm); EXPX(u1[3], mm);
            EXPX(u2[0], mm); EXPX(u2[1], mm); EXPX(u2[2], mm); EXPX(u2[3], mm);
            EXPX(u3[0], mm); EXPX(u3[1], mm); EXPX(u3[2], mm); EXPX(u3[3], mm);
            float psum = ((u0[0] + u0[1]) + (u0[2] + u0[3]))
                       + ((u1[0] + u1[1]) + (u1[2] + u1[3]))
                       + ((u2[0] + u2[1]) + (u2[2] + u2[3]))
                       + ((u3[0] + u3[1]) + (u3[2] + u3[3]));
            ll1 = ll1 * alpha + psum;
            a10 *= alpha; a11 *= alpha;
            p2.w4[0] = cvtpk(u0[0], u0[1]); p2.w4[1] = cvtpk(u0[2], u0[3]);
            p2.w4[2] = cvtpk(u1[0], u1[1]); p2.w4[3] = cvtpk(u1[2], u1[3]);
            p3.w4[0] = cvtpk(u2[0], u2[1]); p3.w4[1] = cvtpk(u2[2], u2[3]);
            p3.w4[2] = cvtpk(u3[0], u3[1]); p3.w4[3] = cvtpk(u3[2], u3[3]);
        }
#undef EXPX

        // ---- PV: O^T += Vt x P, shared Vt fragments feed both q-fragments ----
#pragma unroll
        for (int dt = 0; dt < 2; ++dt) {
            int dd = dt * 16 + lr;
#pragma unroll
            for (int ks = 0; ks < 2; ++ks) {
                uint2 va0 = *(const uint2*)(VL + dd * 64 + ((ks * 8 + lg)     ^ lr) * 4);
                uint2 va1 = *(const uint2*)(VL + dd * 64 + ((ks * 8 + 4 + lg) ^ lr) * 4);
                PB va;
                va.w4[0] = va0.x; va.w4[1] = va0.y; va.w4[2] = va1.x; va.w4[3] = va1.y;
                f32x4& c0 = dt ? a01 : a00;
                f32x4& c1 = dt ? a11 : a10;
                c0 = __builtin_amdgcn_mfma_f32_16x16x32_bf16(va.v, (ks ? p1 : p0).v, c0, 0, 0, 0);
                c1 = __builtin_amdgcn_mfma_f32_16x16x32_bf16(va.v, (ks ? p3 : p2).v, c1, 0, 0, 0);
            }
        }
    }
    __syncthreads();   // all tile readers done before epilogue smem reuse

    // ---- epilogue: reduce l, normalize, per-wave LDS transpose, coalesced store + residual ----
    ll0 += __shfl_xor(ll0, 16); ll0 += __shfl_xor(ll0, 32);
    ll1 += __shfl_xor(ll1, 16); ll1 += __shfl_xor(ll1, 32);
    float inv0 = 1.0f / ll0, inv1 = 1.0f / ll1;
    a00 *= inv0; a01 *= inv0; a10 *= inv1; a11 *= inv1;

    float* OW = (float*)smem + w * 512;   // per-wave 16q x 32d tile, 16B-chunk swizzle ^(q&7)
    int q = l & 15, part = l >> 4;
    {   // pass qf0
        *(f32x4*)(OW + lr * 32 + ((lg    ) ^ (lr & 7)) * 4) = a00;
        *(f32x4*)(OW + lr * 32 + ((4 + lg) ^ (lr & 7)) * 4) = a01;
        f32x4 r0 = *(const f32x4*)(OW + q * 32 + ((2 * part    ) ^ (q & 7)) * 4);
        f32x4 r1 = *(const f32x4*)(OW + q * 32 + ((2 * part + 1) ^ (q & 7)) * 4);
        size_t gbase = ((size_t)b * NN + q0w + q) * CC + hh * 32 + part * 8;
        f32x4 x0 = *(const f32x4*)(x + gbase);
        f32x4 x1 = *(const f32x4*)(x + gbase + 4);
        *(f32x4*)(out + gbase)     = r0 + x0;
        *(f32x4*)(out + gbase + 4) = r1 + x1;
    }
    {   // pass qf1 (same-wave region; program order guarantees pass-0 reads complete)
        *(f32x4*)(OW + lr * 32 + ((lg    ) ^ (lr & 7)) * 4) = a10;
        *(f32x4*)(OW + lr * 32 + ((4 + lg) ^ (lr & 7)) * 4) = a11;
        f32x4 r0 = *(const f32x4*)(OW + q * 32 + ((2 * part    ) ^ (q & 7)) * 4);
        f32x4 r1 = *(const f32x4*)(OW + q * 32 + ((2 * part + 1) ^ (q & 7)) * 4);
        size_t gbase = ((size_t)b * NN + q0w + 16 + q) * CC + hh * 32 + part * 8;
        f32x4 x0 = *(const f32x4*)(x + gbase);
        f32x4 x1 = *(const f32x4*)(x + gbase + 4);
        *(f32x4*)(out + gbase)     = r0 + x0;
        *(f32x4*)(out + gbase + 4) = r1 + x1;
    }
}

// ---------------- launch ----------------
extern "C" void kernel_launch(void* const* d_in, const int* in_sizes, int n_in,
                              void* d_out, int out_size, void* d_ws, size_t ws_size,
                              hipStream_t stream) {
    const float* x   = (const float*)d_in[0];
    const float* W   = (const float*)d_in[1];
    const float* bia = (const float*)d_in[2];
    float* out = (float*)d_out;

    char* ws = (char*)d_ws;
    size_t off = 0;
    u16* t_bf  = (u16*)(ws + off); off += (size_t)NTOK * CC * 2;          // 4 MB
    u16* Wt_bf = (u16*)(ws + off); off += (size_t)384 * 128 * 2;          // 96 KB
    u16* Qb    = (u16*)(ws + off); off += (size_t)BB * HH * NN * HD * 2;  // 4 MB
    u16* Kb    = (u16*)(ws + off); off += (size_t)BB * HH * NN * HD * 2;  // 4 MB
    u16* Vtb   = (u16*)(ws + off); off += (size_t)BB * HH * NN * HD * 2;  // 4 MB

    hipLaunchKernelGGL(prep_kernel, dim3(524), dim3(256), 0, stream, x, W, t_bf, Wt_bf);
    hipLaunchKernelGGL(qkv_gemm, dim3(128, 3), dim3(256), 0, stream, t_bf, Wt_bf, bia, Qb, Kb, Vtb);
    hipLaunchKernelGGL(attn_kernel, dim3(16, 32), dim3(256), 0, stream, Qb, Kb, Vtb, x, out);
}